// Round 13
// baseline (398.593 us; speedup 1.0000x reference)
//
#include <hip/hip_runtime.h>
#include <hip/hip_fp16.h>

typedef short s16x8 __attribute__((ext_vector_type(8)));   // 8 bf16 = 4 VGPRs
typedef float fx4 __attribute__((ext_vector_type(4)));     // MFMA acc

#define AS_G(p) ((const __attribute__((address_space(1))) void*)(p))
#define AS_L(p) ((__attribute__((address_space(3))) void*)(p))

struct __align__(8) half4 { __half2 lo, hi; };

__device__ inline unsigned short f32_to_bf16(float f) {
    unsigned int u = __float_as_uint(f);
    return (unsigned short)((u + 0x7fffu + ((u >> 16) & 1u)) >> 16);
}
__device__ inline float bf16_to_f32(unsigned short b) {
    return __uint_as_float(((unsigned int)b) << 16);
}
__device__ inline void split2(float a, unsigned short& hi, unsigned short& lo) {
    hi = f32_to_bf16(a);
    lo = f32_to_bf16(a - bf16_to_f32(hi));
}

// ===================== graph preprocessing =====================

// fused dispatch: blocks [0,degB) histogram degrees; blocks [degB,..) convert x -> fp16.
__global__ void k_degx(const int* __restrict__ dst, int E, int* __restrict__ deg, int degB,
                       const float* __restrict__ x, __half* __restrict__ xh, int nx) {
    if (blockIdx.x < (unsigned)degB) {
        int i = blockIdx.x * 256 + threadIdx.x;
        if (i < E) atomicAdd(&deg[dst[i]], 1);
    } else {
        int i = (blockIdx.x - degB) * 1024 + threadIdx.x * 4;
        if (i < nx) {
            float4 v = *(const float4*)&x[i];
            __half2 h0(__float2half(v.x), __float2half(v.y));
            __half2 h1(__float2half(v.z), __float2half(v.w));
            *(__half2*)&xh[i] = h0;
            *(__half2*)&xh[i + 2] = h1;
        }
    }
}

// fused dispatch: blocks [0,nb) do deg-scan + dinv; blocks [nb,..) split/transpose weights.
__global__ void k_scan1w(const int* __restrict__ deg, int N, int nb,
                         int* __restrict__ part, int* __restrict__ bsum, float* __restrict__ dinv,
                         const float* __restrict__ W0, unsigned short* __restrict__ h0, unsigned short* __restrict__ l0,
                         const float* __restrict__ W1, unsigned short* __restrict__ h1, unsigned short* __restrict__ l1,
                         const float* __restrict__ W2, unsigned short* __restrict__ h2, unsigned short* __restrict__ l2,
                         int DIN, int DH) {
    __shared__ int s[256];
    if (blockIdx.x < (unsigned)nb) {
        int i = blockIdx.x * 256 + threadIdx.x;
        int v = (i < N) ? deg[i] : 0;
        if (i < N) dinv[i] = 1.0f / sqrtf((float)(v + 1));  // +1 self-loop
        s[threadIdx.x] = v;
        __syncthreads();
        for (int off = 1; off < 256; off <<= 1) {
            int t = (threadIdx.x >= off) ? s[threadIdx.x - off] : 0;
            __syncthreads();
            s[threadIdx.x] += t;
            __syncthreads();
        }
        if (i < N) part[i] = s[threadIdx.x] - v;
        if (threadIdx.x == 255) bsum[blockIdx.x] = s[255];
    } else {
        int i = (blockIdx.x - nb) * 256 + threadIdx.x;
        const int n0 = DIN * DH, n1 = DH * DH;
        const float* W; unsigned short *hT, *lT; int K, li;
        if (i < n0) { W = W0; hT = h0; lT = l0; K = DIN; li = i; }
        else if (i < n0 + n1) { W = W1; hT = h1; lT = l1; K = DH; li = i - n0; }
        else if (i < n0 + 2 * n1) { W = W2; hT = h2; lT = l2; K = DH; li = i - n0 - n1; }
        else return;
        int k = li / DH, n = li - k * DH;
        unsigned short h, l;
        split2(W[li], h, l);
        hT[(size_t)n * K + k] = h;
        lT[(size_t)n * K + k] = l;
    }
}

// rowptr build without a separate bsum-scan kernel: each block reduces the raw
// per-block sums for blocks < blockIdx.x itself (nb <= 256).
__global__ void k_scan3(const int* __restrict__ part, const int* __restrict__ bsum, int nb,
                        int N, int E, int* __restrict__ rowptr, int* __restrict__ cursor) {
    __shared__ int s[256];
    const int t = threadIdx.x;
    s[t] = (t < nb && t < (int)blockIdx.x) ? bsum[t] : 0;
    __syncthreads();
    for (int off = 128; off > 0; off >>= 1) {
        if (t < off) s[t] += s[t + off];
        __syncthreads();
    }
    const int base = s[0];
    int i = blockIdx.x * 256 + t;
    if (i < N) {
        int v = part[i] + base;
        rowptr[i] = v;
        cursor[i] = v;
    }
    if (i == 0) rowptr[N] = E;
}

__global__ void k_fill(const int* __restrict__ src, const int* __restrict__ dst, int E,
                       const float* __restrict__ dinv, int* __restrict__ cursor,
                       int* __restrict__ col, float* __restrict__ nrm) {
    int e = blockIdx.x * blockDim.x + threadIdx.x;
    if (e < E) {
        int s = src[e], d = dst[e];
        int p = atomicAdd(&cursor[d], 1);
        col[p] = s;
        nrm[p] = dinv[s] * dinv[d];
    }
}

// ===================== split-bf16 MFMA GEMM, DOUBLE-BUFFERED, fused bias/ReLU, fp16 out ===
// Per 32-K chunk: issue chunk t+1's global_load_lds into the other 32KB buffer, THEN
// compute chunk t, THEN one barrier (its vmcnt drain lands after compute covered the
// latency). Replaces the single-buffer [stage; drain; compute; barrier] serialization.
// LDS 2x32KB = 64KB -> 2 blocks/CU.

__global__ __launch_bounds__(256) void k_gemm_mfma(
    const unsigned short* __restrict__ Ahi, const unsigned short* __restrict__ Alo,
    const unsigned short* __restrict__ BhiT, const unsigned short* __restrict__ BloT,
    const float* __restrict__ bias, __half* __restrict__ C, int Nrows, int K) {
    __shared__ __align__(16) unsigned short smem[2][4][128 * 32];  // [buf][arr][tile]

    const int tid = threadIdx.x;
    const int wid = tid >> 6, lane = tid & 63;
    const int row0 = blockIdx.y * 128;
    const int col0 = blockIdx.x * 128;
    const int wrow = wid & 1, wcol = wid >> 1;
    const int quad = lane >> 4, l16 = lane & 15;

    const unsigned short* garr = (wid == 0) ? Ahi : (wid == 1) ? Alo : (wid == 2) ? BhiT : BloT;
    const bool isA = (wid < 2);

    const unsigned short* gp[8];
#pragma unroll
    for (int i = 0; i < 8; ++i) {
        int r = 16 * i + (lane >> 2);
        int s = lane & 3;
        int q = (s - (r >> 1)) & 3;              // XOR bank-swizzle in global address
        int grow = isA ? min(row0 + r, Nrows - 1) : (col0 + r);
        gp[i] = garr + (size_t)grow * K + q * 8;
    }

    int aidx[4], bidx[4];
#pragma unroll
    for (int t = 0; t < 4; ++t) {
        int ra = wrow * 64 + t * 16 + l16;
        aidx[t] = ra * 32 + ((quad + (ra >> 1)) & 3) * 8;
        int rb = wcol * 64 + t * 16 + l16;
        bidx[t] = rb * 32 + ((quad + (rb >> 1)) & 3) * 8;
    }

    fx4 acc[4][4] = {};
    const int nch = K / 32;

    // prologue: stage chunk 0 into buf 0
#pragma unroll
    for (int i = 0; i < 8; ++i)
        __builtin_amdgcn_global_load_lds(AS_G(gp[i]), AS_L((char*)smem[0][wid] + i * 1024), 16, 0, 0);
    __syncthreads();

    for (int t = 0; t < nch; ++t) {
        const int buf = t & 1;
        if (t + 1 < nch) {
#pragma unroll
            for (int i = 0; i < 8; ++i)
                __builtin_amdgcn_global_load_lds(AS_G(gp[i] + (t + 1) * 32),
                                                 AS_L((char*)smem[1 - buf][wid] + i * 1024), 16, 0, 0);
        }

        const unsigned short* sAhi = smem[buf][0];
        const unsigned short* sAlo = smem[buf][1];
        const unsigned short* sBhi = smem[buf][2];
        const unsigned short* sBlo = smem[buf][3];

        s16x8 ah[4], al[4];
#pragma unroll
        for (int mi = 0; mi < 4; ++mi) {
            ah[mi] = *(const s16x8*)&sAhi[aidx[mi]];
            al[mi] = *(const s16x8*)&sAlo[aidx[mi]];
        }
#pragma unroll
        for (int nj = 0; nj < 4; ++nj) {
            s16x8 bh = *(const s16x8*)&sBhi[bidx[nj]];
            s16x8 bl = *(const s16x8*)&sBlo[bidx[nj]];
#pragma unroll
            for (int mi = 0; mi < 4; ++mi) {
                acc[mi][nj] = __builtin_amdgcn_mfma_f32_16x16x32_bf16(ah[mi], bh, acc[mi][nj], 0, 0, 0);
                acc[mi][nj] = __builtin_amdgcn_mfma_f32_16x16x32_bf16(ah[mi], bl, acc[mi][nj], 0, 0, 0);
                acc[mi][nj] = __builtin_amdgcn_mfma_f32_16x16x32_bf16(al[mi], bh, acc[mi][nj], 0, 0, 0);
            }
        }
        if (t + 1 < nch) __syncthreads();
    }

    // C/D layout: col = lane&15, row = quad*4 + reg  [m89-verified]
#pragma unroll
    for (int mi = 0; mi < 4; ++mi) {
        const int rbase = row0 + wrow * 64 + mi * 16 + quad * 4;
#pragma unroll
        for (int nj = 0; nj < 4; ++nj) {
            const int c = col0 + wcol * 64 + nj * 16 + l16;
            const float bc = bias[c];
#pragma unroll
            for (int reg = 0; reg < 4; ++reg) {
                int r = rbase + reg;
                if (r < Nrows) C[(size_t)r * 256 + c] = __float2half(fmaxf(acc[mi][nj][reg] + bc, 0.f));
            }
        }
    }
}

// Layer-2 variant: relu(acc+bias) pooled per-graph into gsum[64][256] (double-buffered
// identically; epilogue = segment reduction + cross-quad shfl + atomicAdd).
__global__ __launch_bounds__(256) void k_gemm_pool(
    const unsigned short* __restrict__ Ahi, const unsigned short* __restrict__ Alo,
    const unsigned short* __restrict__ BhiT, const unsigned short* __restrict__ BloT,
    const float* __restrict__ bias, const int* __restrict__ batch,
    float* __restrict__ gsum, int Nrows, int K) {
    __shared__ __align__(16) unsigned short smem[2][4][128 * 32];

    const int tid = threadIdx.x;
    const int wid = tid >> 6, lane = tid & 63;
    const int row0 = blockIdx.y * 128;
    const int col0 = blockIdx.x * 128;
    const int wrow = wid & 1, wcol = wid >> 1;
    const int quad = lane >> 4, l16 = lane & 15;

    const unsigned short* garr = (wid == 0) ? Ahi : (wid == 1) ? Alo : (wid == 2) ? BhiT : BloT;
    const bool isA = (wid < 2);

    const unsigned short* gp[8];
#pragma unroll
    for (int i = 0; i < 8; ++i) {
        int r = 16 * i + (lane >> 2);
        int s = lane & 3;
        int q = (s - (r >> 1)) & 3;
        int grow = isA ? min(row0 + r, Nrows - 1) : (col0 + r);
        gp[i] = garr + (size_t)grow * K + q * 8;
    }

    int aidx[4], bidx[4];
#pragma unroll
    for (int t = 0; t < 4; ++t) {
        int ra = wrow * 64 + t * 16 + l16;
        aidx[t] = ra * 32 + ((quad + (ra >> 1)) & 3) * 8;
        int rb = wcol * 64 + t * 16 + l16;
        bidx[t] = rb * 32 + ((quad + (rb >> 1)) & 3) * 8;
    }

    fx4 acc[4][4] = {};
    const int nch = K / 32;

#pragma unroll
    for (int i = 0; i < 8; ++i)
        __builtin_amdgcn_global_load_lds(AS_G(gp[i]), AS_L((char*)smem[0][wid] + i * 1024), 16, 0, 0);
    __syncthreads();

    for (int t = 0; t < nch; ++t) {
        const int buf = t & 1;
        if (t + 1 < nch) {
#pragma unroll
            for (int i = 0; i < 8; ++i)
                __builtin_amdgcn_global_load_lds(AS_G(gp[i] + (t + 1) * 32),
                                                 AS_L((char*)smem[1 - buf][wid] + i * 1024), 16, 0, 0);
        }

        const unsigned short* sAhi = smem[buf][0];
        const unsigned short* sAlo = smem[buf][1];
        const unsigned short* sBhi = smem[buf][2];
        const unsigned short* sBlo = smem[buf][3];

        s16x8 ah[4], al[4];
#pragma unroll
        for (int mi = 0; mi < 4; ++mi) {
            ah[mi] = *(const s16x8*)&sAhi[aidx[mi]];
            al[mi] = *(const s16x8*)&sAlo[aidx[mi]];
        }
#pragma unroll
        for (int nj = 0; nj < 4; ++nj) {
            s16x8 bh = *(const s16x8*)&sBhi[bidx[nj]];
            s16x8 bl = *(const s16x8*)&sBlo[bidx[nj]];
#pragma unroll
            for (int mi = 0; mi < 4; ++mi) {
                acc[mi][nj] = __builtin_amdgcn_mfma_f32_16x16x32_bf16(ah[mi], bh, acc[mi][nj], 0, 0, 0);
                acc[mi][nj] = __builtin_amdgcn_mfma_f32_16x16x32_bf16(ah[mi], bl, acc[mi][nj], 0, 0, 0);
                acc[mi][nj] = __builtin_amdgcn_mfma_f32_16x16x32_bf16(al[mi], bh, acc[mi][nj], 0, 0, 0);
            }
        }
        if (t + 1 < nch) __syncthreads();
    }

    int bg[4][4];
#pragma unroll
    for (int mi = 0; mi < 4; ++mi)
#pragma unroll
        for (int reg = 0; reg < 4; ++reg) {
            int r = row0 + wrow * 64 + mi * 16 + quad * 4 + reg;
            bg[mi][reg] = (r < Nrows) ? batch[r] : -1;
        }
    const int gfirst = batch[row0 < Nrows ? row0 : (Nrows - 1)];
    const int glast  = batch[min(row0 + 127, Nrows - 1)];

#pragma unroll
    for (int nj = 0; nj < 4; ++nj) {
        const int c = col0 + wcol * 64 + nj * 16 + l16;
        const float bc = bias[c];
        for (int g = gfirst; g <= glast; ++g) {
            float s = 0.f;
#pragma unroll
            for (int mi = 0; mi < 4; ++mi)
#pragma unroll
                for (int reg = 0; reg < 4; ++reg)
                    if (bg[mi][reg] == g) s += fmaxf(acc[mi][nj][reg] + bc, 0.f);
            s += __shfl_xor(s, 16);
            s += __shfl_xor(s, 32);
            if (quad == 0) atomicAdd(&gsum[g * 256 + c], s);
        }
    }
}

// ===================== aggregation (fp16 gather, fp32 accumulate) =====================
// WAVE-PER-NODE (proven best: r8 persistent and r11 paired-node were neutral/worse —
// fabric-limited; fp16 rows already halved traffic).

// D=256: wave per node, lane owns half4 (8B); 8 gathers in flight.
__global__ __launch_bounds__(256) void k_agg256(const __half* __restrict__ H, const int* __restrict__ rowptr,
                                                const int* __restrict__ col, const float* __restrict__ nrm,
                                                const float* __restrict__ dinv,
                                                unsigned short* __restrict__ outHi,
                                                unsigned short* __restrict__ outLo, int N) {
    const int wave = threadIdx.x >> 6, lane = threadIdx.x & 63;
    const int v = blockIdx.x * 4 + wave;
    if (v >= N) return;

    const float di = dinv[v];
    const float selfn = di * di;
    half4 hv = ((const half4*)&H[(size_t)v * 256])[lane];
    float2 s0 = __half22float2(hv.lo), s1 = __half22float2(hv.hi);
    float ax = selfn * s0.x, ay = selfn * s0.y, az = selfn * s1.x, aw = selfn * s1.y;

    int e = rowptr[v];
    const int end = rowptr[v + 1];
    for (; e + 8 <= end; e += 8) {
        int u[8]; float w[8]; half4 g[8];
#pragma unroll
        for (int j = 0; j < 8; ++j) { u[j] = col[e + j]; w[j] = nrm[e + j]; }
#pragma unroll
        for (int j = 0; j < 8; ++j) g[j] = ((const half4*)&H[(size_t)u[j] * 256])[lane];
#pragma unroll
        for (int j = 0; j < 8; ++j) {
            float2 f0 = __half22float2(g[j].lo), f1 = __half22float2(g[j].hi);
            ax += w[j] * f0.x; ay += w[j] * f0.y; az += w[j] * f1.x; aw += w[j] * f1.y;
        }
    }
    for (; e < end; ++e) {
        const int u = col[e];
        const float w = nrm[e];
        half4 g = ((const half4*)&H[(size_t)u * 256])[lane];
        float2 f0 = __half22float2(g.lo), f1 = __half22float2(g.hi);
        ax += w * f0.x; ay += w * f0.y; az += w * f1.x; aw += w * f1.y;
    }

    ushort4 hi4, lo4;
    split2(ax, hi4.x, lo4.x);
    split2(ay, hi4.y, lo4.y);
    split2(az, hi4.z, lo4.z);
    split2(aw, hi4.w, lo4.w);
    ((ushort4*)outHi)[(size_t)v * 64 + lane] = hi4;
    ((ushort4*)outLo)[(size_t)v * 64 + lane] = lo4;
}

// D=128: half-wave per node on fp16 x (256B rows), lane owns half4; 4-deep unroll.
__global__ __launch_bounds__(256) void k_agg128(const __half* __restrict__ X, const int* __restrict__ rowptr,
                                                const int* __restrict__ col, const float* __restrict__ nrm,
                                                const float* __restrict__ dinv,
                                                unsigned short* __restrict__ outHi,
                                                unsigned short* __restrict__ outLo, int N) {
    const int half = threadIdx.x >> 5, sub = threadIdx.x & 31;
    const int v = blockIdx.x * 8 + half;
    if (v >= N) return;

    const float di = dinv[v];
    const float selfn = di * di;
    half4 hv = ((const half4*)&X[(size_t)v * 128])[sub];
    float2 s0 = __half22float2(hv.lo), s1 = __half22float2(hv.hi);
    float ax = selfn * s0.x, ay = selfn * s0.y, az = selfn * s1.x, aw = selfn * s1.y;

    int e = rowptr[v];
    const int end = rowptr[v + 1];
    for (; e + 4 <= end; e += 4) {
        int u[4]; float w[4]; half4 g[4];
#pragma unroll
        for (int j = 0; j < 4; ++j) { u[j] = col[e + j]; w[j] = nrm[e + j]; }
#pragma unroll
        for (int j = 0; j < 4; ++j) g[j] = ((const half4*)&X[(size_t)u[j] * 128])[sub];
#pragma unroll
        for (int j = 0; j < 4; ++j) {
            float2 f0 = __half22float2(g[j].lo), f1 = __half22float2(g[j].hi);
            ax += w[j] * f0.x; ay += w[j] * f0.y; az += w[j] * f1.x; aw += w[j] * f1.y;
        }
    }
    for (; e < end; ++e) {
        const int u = col[e];
        const float w = nrm[e];
        half4 g = ((const half4*)&X[(size_t)u * 128])[sub];
        float2 f0 = __half22float2(g.lo), f1 = __half22float2(g.hi);
        ax += w * f0.x; ay += w * f0.y; az += w * f1.x; aw += w * f1.y;
    }

    ushort4 hi4, lo4;
    split2(ax, hi4.x, lo4.x);
    split2(ay, hi4.y, lo4.y);
    split2(az, hi4.z, lo4.z);
    split2(aw, hi4.w, lo4.w);
    ((ushort4*)outHi)[(size_t)v * 32 + sub] = hi4;
    ((ushort4*)outLo)[(size_t)v * 32 + sub] = lo4;
}

// ===================== fused mean-pool finalize + classifier head =====================
// graph bounds via inline binary search over sorted batch (replaces gstart buffer).

__global__ __launch_bounds__(256) void k_poolcls(const float* __restrict__ gsum, const int* __restrict__ batch,
                                                 int N,
                                                 const float* __restrict__ Wc1, const float* __restrict__ bc1,
                                                 const float* __restrict__ Wc2, const float* __restrict__ bc2,
                                                 float* __restrict__ out) {
    __shared__ float sg[256], sh[256];
    __shared__ int bounds[2];
    const int b = blockIdx.x, t = threadIdx.x;
    if (t < 2) {
        int target = b + t;
        int lo = 0, hi = N;
        while (lo < hi) {
            int mid = (lo + hi) >> 1;
            if (batch[mid] < target) lo = mid + 1; else hi = mid;
        }
        bounds[t] = lo;
    }
    __syncthreads();
    const float c = (float)(bounds[1] - bounds[0]);
    sg[t] = gsum[b * 256 + t] / fmaxf(c, 1.0f);
    __syncthreads();
    float acc = bc1[t];
    for (int k = 0; k < 256; ++k) acc += sg[k] * Wc1[k * 256 + t];
    sh[t] = fmaxf(acc, 0.f);
    __syncthreads();
    if (t < 5) {
        float o = bc2[t];
        for (int k = 0; k < 256; ++k) o += sh[k] * Wc2[k * 5 + t];
        out[b * 5 + t] = o;
    }
}

// ===================== launch =====================

extern "C" void kernel_launch(void* const* d_in, const int* in_sizes, int n_in,
                              void* d_out, int out_size, void* d_ws, size_t ws_size,
                              hipStream_t stream) {
    const float* x    = (const float*)d_in[0];
    const int*   eidx = (const int*)d_in[1];
    const int*   batch= (const int*)d_in[2];
    const float* W0 = (const float*)d_in[3];  const float* b0 = (const float*)d_in[4];
    const float* W1 = (const float*)d_in[5];  const float* b1 = (const float*)d_in[6];
    const float* W2 = (const float*)d_in[7];  const float* b2 = (const float*)d_in[8];
    const float* Wc1= (const float*)d_in[9];  const float* bc1= (const float*)d_in[10];
    const float* Wc2= (const float*)d_in[11]; const float* bc2= (const float*)d_in[12];
    float* out = (float*)d_out;

    const int N   = in_sizes[2];       // 50000
    const int E   = in_sizes[1] / 2;   // 500000
    const int DIN = in_sizes[0] / N;   // 128
    const int DH  = in_sizes[4];       // 256
    const int* src = eidx;
    const int* dst = eidx + E;

    char* p = (char*)d_ws;
    auto alloc = [&](size_t bytes) {
        char* r = p;
        p += (bytes + 255) & ~(size_t)255;
        return (void*)r;
    };
    __half*         hbuf = (__half*)alloc((size_t)N * DH * 2);          // gemm out (fp16), agg gather in
    __half*         xh   = (__half*)alloc((size_t)N * DIN * 2);         // x in fp16
    unsigned short* hhi  = (unsigned short*)alloc((size_t)N * DH * 2);  // agg split out / gemm A in
    unsigned short* hlo  = (unsigned short*)alloc((size_t)N * DH * 2);
    unsigned short* w0hi = (unsigned short*)alloc((size_t)DH * DIN * 2);
    unsigned short* w0lo = (unsigned short*)alloc((size_t)DH * DIN * 2);
    unsigned short* w1hi = (unsigned short*)alloc((size_t)DH * DH * 2);
    unsigned short* w1lo = (unsigned short*)alloc((size_t)DH * DH * 2);
    unsigned short* w2hi = (unsigned short*)alloc((size_t)DH * DH * 2);
    unsigned short* w2lo = (unsigned short*)alloc((size_t)DH * DH * 2);
    int*   deg   = (int*)alloc((size_t)N * 4);
    float* gsum  = (float*)alloc(64 * (size_t)DH * 4);   // adjacent to deg: one memset covers both
    float* dinv  = (float*)alloc((size_t)N * 4);
    int*   part  = (int*)alloc((size_t)N * 4);
    int*   bsum  = (int*)alloc(256 * 4);
    int*   rowptr= (int*)alloc((size_t)(N + 1) * 4);
    int*   cursor= (int*)alloc((size_t)N * 4);
    int*   col   = (int*)alloc((size_t)E * 4);
    float* nrm   = (float*)alloc((size_t)E * 4);

    hipMemsetAsync(deg, 0, (size_t)((char*)gsum - (char*)deg) + 64 * (size_t)DH * 4, stream);

    const int nb = (N + 255) / 256;
    const int wtot = DIN * DH + 2 * DH * DH;
    const int wb = (wtot + 255) / 256;
    const int degB = (E + 255) / 256;
    const int nx = N * DIN;
    const int xb = (nx + 1023) / 1024;

    k_degx  <<<degB + xb, 256, 0, stream>>>(dst, E, deg, degB, x, xh, nx);
    k_scan1w<<<nb + wb, 256, 0, stream>>>(deg, N, nb, part, bsum, dinv,
                                          W0, w0hi, w0lo, W1, w1hi, w1lo, W2, w2hi, w2lo, DIN, DH);
    k_scan3 <<<nb, 256, 0, stream>>>(part, bsum, nb, N, E, rowptr, cursor);
    k_fill  <<<(E + 255) / 256, 256, 0, stream>>>(src, dst, E, dinv, cursor, col, nrm);

    dim3 gemmGrid(DH / 128, (N + 127) / 128);

    // layer 0: agg(x fp16) -> gemm(relu(.W0+b0)) -> fp16 H
    k_agg128<<<(N + 7) / 8, 256, 0, stream>>>(xh, rowptr, col, nrm, dinv, hhi, hlo, N);
    k_gemm_mfma<<<gemmGrid, 256, 0, stream>>>(hhi, hlo, w0hi, w0lo, b0, hbuf, N, DIN);
    // layer 1
    k_agg256<<<(N + 3) / 4, 256, 0, stream>>>(hbuf, rowptr, col, nrm, dinv, hhi, hlo, N);
    k_gemm_mfma<<<gemmGrid, 256, 0, stream>>>(hhi, hlo, w1hi, w1lo, b1, hbuf, N, DH);
    // layer 2 (fused pooling epilogue)
    k_agg256<<<(N + 3) / 4, 256, 0, stream>>>(hbuf, rowptr, col, nrm, dinv, hhi, hlo, N);
    k_gemm_pool<<<gemmGrid, 256, 0, stream>>>(hhi, hlo, w2hi, w2lo, b2, batch, gsum, N, DH);

    k_poolcls<<<64, 256, 0, stream>>>(gsum, batch, N, Wc1, bc1, Wc2, bc2, out);
}

// Round 14
// 369.569 us; speedup vs baseline: 1.0785x; 1.0785x over previous
//
#include <hip/hip_runtime.h>
#include <hip/hip_fp16.h>

typedef _Float16 f16x8 __attribute__((ext_vector_type(8)));  // 8 fp16 = 4 VGPRs (MFMA A/B)
typedef float fx4 __attribute__((ext_vector_type(4)));       // MFMA acc

#define AS_G(p) ((const __attribute__((address_space(1))) void*)(p))
#define AS_L(p) ((__attribute__((address_space(3))) void*)(p))

struct __align__(8) half4 { __half2 lo, hi; };

// fp16 two-term split for weights: hi = fp16(w), lo = fp16(w - hi)  (combined ~2^-23 rel)
__device__ inline void split2h(float a, __half& hi, __half& lo) {
    hi = __float2half(a);
    lo = __float2half(a - __half2float(hi));
}

// ===================== graph preprocessing =====================

// fused dispatch: blocks [0,degB) histogram degrees; blocks [degB,..) convert x -> fp16.
__global__ void k_degx(const int* __restrict__ dst, int E, int* __restrict__ deg, int degB,
                       const float* __restrict__ x, __half* __restrict__ xh, int nx) {
    if (blockIdx.x < (unsigned)degB) {
        int i = blockIdx.x * 256 + threadIdx.x;
        if (i < E) atomicAdd(&deg[dst[i]], 1);
    } else {
        int i = (blockIdx.x - degB) * 1024 + threadIdx.x * 4;
        if (i < nx) {
            float4 v = *(const float4*)&x[i];
            __half2 h0(__float2half(v.x), __float2half(v.y));
            __half2 h1(__float2half(v.z), __float2half(v.w));
            *(__half2*)&xh[i] = h0;
            *(__half2*)&xh[i + 2] = h1;
        }
    }
}

// fused dispatch: blocks [0,nb) deg-scan + dinv; blocks [nb,..) split/transpose weights to fp16 hi/lo.
__global__ void k_scan1w(const int* __restrict__ deg, int N, int nb,
                         int* __restrict__ part, int* __restrict__ bsum, float* __restrict__ dinv,
                         const float* __restrict__ W0, __half* __restrict__ h0, __half* __restrict__ l0,
                         const float* __restrict__ W1, __half* __restrict__ h1, __half* __restrict__ l1,
                         const float* __restrict__ W2, __half* __restrict__ h2, __half* __restrict__ l2,
                         int DIN, int DH) {
    __shared__ int s[256];
    if (blockIdx.x < (unsigned)nb) {
        int i = blockIdx.x * 256 + threadIdx.x;
        int v = (i < N) ? deg[i] : 0;
        if (i < N) dinv[i] = 1.0f / sqrtf((float)(v + 1));  // +1 self-loop
        s[threadIdx.x] = v;
        __syncthreads();
        for (int off = 1; off < 256; off <<= 1) {
            int t = (threadIdx.x >= off) ? s[threadIdx.x - off] : 0;
            __syncthreads();
            s[threadIdx.x] += t;
            __syncthreads();
        }
        if (i < N) part[i] = s[threadIdx.x] - v;
        if (threadIdx.x == 255) bsum[blockIdx.x] = s[255];
    } else {
        int i = (blockIdx.x - nb) * 256 + threadIdx.x;
        const int n0 = DIN * DH, n1 = DH * DH;
        const float* W; __half *hT, *lT; int K, li;
        if (i < n0) { W = W0; hT = h0; lT = l0; K = DIN; li = i; }
        else if (i < n0 + n1) { W = W1; hT = h1; lT = l1; K = DH; li = i - n0; }
        else if (i < n0 + 2 * n1) { W = W2; hT = h2; lT = l2; K = DH; li = i - n0 - n1; }
        else return;
        int k = li / DH, n = li - k * DH;
        __half h, l;
        split2h(W[li], h, l);
        hT[(size_t)n * K + k] = h;
        lT[(size_t)n * K + k] = l;
    }
}

// rowptr build; each block reduces the raw per-block sums itself (nb <= 256).
__global__ void k_scan3(const int* __restrict__ part, const int* __restrict__ bsum, int nb,
                        int N, int E, int* __restrict__ rowptr, int* __restrict__ cursor) {
    __shared__ int s[256];
    const int t = threadIdx.x;
    s[t] = (t < nb && t < (int)blockIdx.x) ? bsum[t] : 0;
    __syncthreads();
    for (int off = 128; off > 0; off >>= 1) {
        if (t < off) s[t] += s[t + off];
        __syncthreads();
    }
    const int base = s[0];
    int i = blockIdx.x * 256 + t;
    if (i < N) {
        int v = part[i] + base;
        rowptr[i] = v;
        cursor[i] = v;
    }
    if (i == 0) rowptr[N] = E;
}

__global__ void k_fill(const int* __restrict__ src, const int* __restrict__ dst, int E,
                       const float* __restrict__ dinv, int* __restrict__ cursor,
                       int* __restrict__ col, float* __restrict__ nrm) {
    int e = blockIdx.x * blockDim.x + threadIdx.x;
    if (e < E) {
        int s = src[e], d = dst[e];
        int p = atomicAdd(&cursor[d], 1);
        col[p] = s;
        nrm[p] = dinv[s] * dinv[d];
    }
}

// ===================== fp16 MFMA GEMM (A single fp16, W fp16 hi+lo), bias/ReLU, fp16 out ===
// C = A*Whi + A*Wlo: 2 MFMAs per tile (was 3 with split-bf16), A traffic halved.
// Single-buffered (r13 dbuf was neutral and halved occupancy). LDS 24KB.
// 24 stage-loads (A:8, Bhi:8, Blo:8) -> 6 per wave; XOR bank-swizzle in global addrs.

__device__ __forceinline__ void gemm_core(
    const __half* __restrict__ Aop, const __half* __restrict__ BhiT, const __half* __restrict__ BloT,
    __half* smem, int Nrows, int K, int row0, int col0,
    int wid, int lane, int wrow, int wcol, int quad, int l16, fx4 (&acc)[4][4]) {
    const __half* gp[6];
    int ldsoff[6];
#pragma unroll
    for (int j = 0; j < 6; ++j) {
        int L = wid * 6 + j;
        int arr = L >> 3, slot = L & 7;
        int r = 16 * slot + (lane >> 2);
        int s = lane & 3;
        int q = (s - (r >> 1)) & 3;              // XOR swizzle folded into global addr
        const __half* garr = (arr == 0) ? Aop : (arr == 1) ? BhiT : BloT;
        int grow = (arr == 0) ? min(row0 + r, Nrows - 1) : (col0 + r);
        gp[j] = garr + (size_t)grow * K + q * 8;
        ldsoff[j] = arr * 8192 + slot * 1024;    // bytes: arr tile 128x32 halfs = 8KB
    }

    const __half* sA   = smem;
    const __half* sBhi = smem + 128 * 32;
    const __half* sBlo = smem + 2 * 128 * 32;

    int aidx[4], bidx[4];
#pragma unroll
    for (int t = 0; t < 4; ++t) {
        int ra = wrow * 64 + t * 16 + l16;
        aidx[t] = ra * 32 + ((quad + (ra >> 1)) & 3) * 8;
        int rb = wcol * 64 + t * 16 + l16;
        bidx[t] = rb * 32 + ((quad + (rb >> 1)) & 3) * 8;
    }

    for (int k0 = 0; k0 < K; k0 += 32) {
#pragma unroll
        for (int j = 0; j < 6; ++j)
            __builtin_amdgcn_global_load_lds(AS_G(gp[j] + k0), AS_L((char*)smem + ldsoff[j]), 16, 0, 0);
        __syncthreads();

        f16x8 a[4];
#pragma unroll
        for (int mi = 0; mi < 4; ++mi) a[mi] = *(const f16x8*)&sA[aidx[mi]];
#pragma unroll
        for (int nj = 0; nj < 4; ++nj) {
            f16x8 bh = *(const f16x8*)&sBhi[bidx[nj]];
            f16x8 bl = *(const f16x8*)&sBlo[bidx[nj]];
#pragma unroll
            for (int mi = 0; mi < 4; ++mi) {
                acc[mi][nj] = __builtin_amdgcn_mfma_f32_16x16x32_f16(a[mi], bh, acc[mi][nj], 0, 0, 0);
                acc[mi][nj] = __builtin_amdgcn_mfma_f32_16x16x32_f16(a[mi], bl, acc[mi][nj], 0, 0, 0);
            }
        }
        __syncthreads();
    }
}

__global__ __launch_bounds__(256) void k_gemm_mfma(
    const __half* __restrict__ Aop, const __half* __restrict__ BhiT, const __half* __restrict__ BloT,
    const float* __restrict__ bias, __half* __restrict__ C, int Nrows, int K) {
    __shared__ __align__(16) __half smem[3 * 128 * 32];
    const int tid = threadIdx.x;
    const int wid = tid >> 6, lane = tid & 63;
    const int row0 = blockIdx.y * 128, col0 = blockIdx.x * 128;
    const int wrow = wid & 1, wcol = wid >> 1;
    const int quad = lane >> 4, l16 = lane & 15;

    fx4 acc[4][4] = {};
    gemm_core(Aop, BhiT, BloT, smem, Nrows, K, row0, col0, wid, lane, wrow, wcol, quad, l16, acc);

    // C/D layout: col = lane&15, row = quad*4 + reg  [m89-verified, dtype-independent]
#pragma unroll
    for (int mi = 0; mi < 4; ++mi) {
        const int rbase = row0 + wrow * 64 + mi * 16 + quad * 4;
#pragma unroll
        for (int nj = 0; nj < 4; ++nj) {
            const int c = col0 + wcol * 64 + nj * 16 + l16;
            const float bc = bias[c];
#pragma unroll
            for (int reg = 0; reg < 4; ++reg) {
                int r = rbase + reg;
                if (r < Nrows) C[(size_t)r * 256 + c] = __float2half(fmaxf(acc[mi][nj][reg] + bc, 0.f));
            }
        }
    }
}

// Layer-2 variant: relu(acc+bias) pooled per-graph into gsum[64][256]
// (segment reduction + cross-quad shfl + atomicAdd; batch sorted).
__global__ __launch_bounds__(256) void k_gemm_pool(
    const __half* __restrict__ Aop, const __half* __restrict__ BhiT, const __half* __restrict__ BloT,
    const float* __restrict__ bias, const int* __restrict__ batch,
    float* __restrict__ gsum, int Nrows, int K) {
    __shared__ __align__(16) __half smem[3 * 128 * 32];
    const int tid = threadIdx.x;
    const int wid = tid >> 6, lane = tid & 63;
    const int row0 = blockIdx.y * 128, col0 = blockIdx.x * 128;
    const int wrow = wid & 1, wcol = wid >> 1;
    const int quad = lane >> 4, l16 = lane & 15;

    fx4 acc[4][4] = {};
    gemm_core(Aop, BhiT, BloT, smem, Nrows, K, row0, col0, wid, lane, wrow, wcol, quad, l16, acc);

    int bg[4][4];
#pragma unroll
    for (int mi = 0; mi < 4; ++mi)
#pragma unroll
        for (int reg = 0; reg < 4; ++reg) {
            int r = row0 + wrow * 64 + mi * 16 + quad * 4 + reg;
            bg[mi][reg] = (r < Nrows) ? batch[r] : -1;
        }
    const int gfirst = batch[row0 < Nrows ? row0 : (Nrows - 1)];
    const int glast  = batch[min(row0 + 127, Nrows - 1)];

#pragma unroll
    for (int nj = 0; nj < 4; ++nj) {
        const int c = col0 + wcol * 64 + nj * 16 + l16;
        const float bc = bias[c];
        for (int g = gfirst; g <= glast; ++g) {
            float s = 0.f;
#pragma unroll
            for (int mi = 0; mi < 4; ++mi)
#pragma unroll
                for (int reg = 0; reg < 4; ++reg)
                    if (bg[mi][reg] == g) s += fmaxf(acc[mi][nj][reg] + bc, 0.f);
            s += __shfl_xor(s, 16);
            s += __shfl_xor(s, 32);
            if (quad == 0) atomicAdd(&gsum[g * 256 + c], s);
        }
    }
}

// ===================== aggregation (fp16 gather, fp32 accumulate, fp16 out) =============
// WAVE-PER-NODE (proven best). Output is now single fp16 (A operand needs no split).

__global__ __launch_bounds__(256) void k_agg256(const __half* __restrict__ H, const int* __restrict__ rowptr,
                                                const int* __restrict__ col, const float* __restrict__ nrm,
                                                const float* __restrict__ dinv,
                                                __half* __restrict__ outA, int N) {
    const int wave = threadIdx.x >> 6, lane = threadIdx.x & 63;
    const int v = blockIdx.x * 4 + wave;
    if (v >= N) return;

    const float di = dinv[v];
    const float selfn = di * di;
    half4 hv = ((const half4*)&H[(size_t)v * 256])[lane];
    float2 s0 = __half22float2(hv.lo), s1 = __half22float2(hv.hi);
    float ax = selfn * s0.x, ay = selfn * s0.y, az = selfn * s1.x, aw = selfn * s1.y;

    int e = rowptr[v];
    const int end = rowptr[v + 1];
    for (; e + 8 <= end; e += 8) {
        int u[8]; float w[8]; half4 g[8];
#pragma unroll
        for (int j = 0; j < 8; ++j) { u[j] = col[e + j]; w[j] = nrm[e + j]; }
#pragma unroll
        for (int j = 0; j < 8; ++j) g[j] = ((const half4*)&H[(size_t)u[j] * 256])[lane];
#pragma unroll
        for (int j = 0; j < 8; ++j) {
            float2 f0 = __half22float2(g[j].lo), f1 = __half22float2(g[j].hi);
            ax += w[j] * f0.x; ay += w[j] * f0.y; az += w[j] * f1.x; aw += w[j] * f1.y;
        }
    }
    for (; e < end; ++e) {
        const int u = col[e];
        const float w = nrm[e];
        half4 g = ((const half4*)&H[(size_t)u * 256])[lane];
        float2 f0 = __half22float2(g.lo), f1 = __half22float2(g.hi);
        ax += w * f0.x; ay += w * f0.y; az += w * f1.x; aw += w * f1.y;
    }

    half4 o;
    o.lo = __floats2half2_rn(ax, ay);
    o.hi = __floats2half2_rn(az, aw);
    ((half4*)outA)[(size_t)v * 64 + lane] = o;
}

__global__ __launch_bounds__(256) void k_agg128(const __half* __restrict__ X, const int* __restrict__ rowptr,
                                                const int* __restrict__ col, const float* __restrict__ nrm,
                                                const float* __restrict__ dinv,
                                                __half* __restrict__ outA, int N) {
    const int half = threadIdx.x >> 5, sub = threadIdx.x & 31;
    const int v = blockIdx.x * 8 + half;
    if (v >= N) return;

    const float di = dinv[v];
    const float selfn = di * di;
    half4 hv = ((const half4*)&X[(size_t)v * 128])[sub];
    float2 s0 = __half22float2(hv.lo), s1 = __half22float2(hv.hi);
    float ax = selfn * s0.x, ay = selfn * s0.y, az = selfn * s1.x, aw = selfn * s1.y;

    int e = rowptr[v];
    const int end = rowptr[v + 1];
    for (; e + 4 <= end; e += 4) {
        int u[4]; float w[4]; half4 g[4];
#pragma unroll
        for (int j = 0; j < 4; ++j) { u[j] = col[e + j]; w[j] = nrm[e + j]; }
#pragma unroll
        for (int j = 0; j < 4; ++j) g[j] = ((const half4*)&X[(size_t)u[j] * 128])[sub];
#pragma unroll
        for (int j = 0; j < 4; ++j) {
            float2 f0 = __half22float2(g[j].lo), f1 = __half22float2(g[j].hi);
            ax += w[j] * f0.x; ay += w[j] * f0.y; az += w[j] * f1.x; aw += w[j] * f1.y;
        }
    }
    for (; e < end; ++e) {
        const int u = col[e];
        const float w = nrm[e];
        half4 g = ((const half4*)&X[(size_t)u * 128])[sub];
        float2 f0 = __half22float2(g.lo), f1 = __half22float2(g.hi);
        ax += w * f0.x; ay += w * f0.y; az += w * f1.x; aw += w * f1.y;
    }

    half4 o;
    o.lo = __floats2half2_rn(ax, ay);
    o.hi = __floats2half2_rn(az, aw);
    ((half4*)outA)[(size_t)v * 32 + sub] = o;
}

// ===================== fused mean-pool finalize + classifier head =====================

__global__ __launch_bounds__(256) void k_poolcls(const float* __restrict__ gsum, const int* __restrict__ batch,
                                                 int N,
                                                 const float* __restrict__ Wc1, const float* __restrict__ bc1,
                                                 const float* __restrict__ Wc2, const float* __restrict__ bc2,
                                                 float* __restrict__ out) {
    __shared__ float sg[256], sh[256];
    __shared__ int bounds[2];
    const int b = blockIdx.x, t = threadIdx.x;
    if (t < 2) {
        int target = b + t;
        int lo = 0, hi = N;
        while (lo < hi) {
            int mid = (lo + hi) >> 1;
            if (batch[mid] < target) lo = mid + 1; else hi = mid;
        }
        bounds[t] = lo;
    }
    __syncthreads();
    const float c = (float)(bounds[1] - bounds[0]);
    sg[t] = gsum[b * 256 + t] / fmaxf(c, 1.0f);
    __syncthreads();
    float acc = bc1[t];
    for (int k = 0; k < 256; ++k) acc += sg[k] * Wc1[k * 256 + t];
    sh[t] = fmaxf(acc, 0.f);
    __syncthreads();
    if (t < 5) {
        float o = bc2[t];
        for (int k = 0; k < 256; ++k) o += sh[k] * Wc2[k * 5 + t];
        out[b * 5 + t] = o;
    }
}

// ===================== launch =====================

extern "C" void kernel_launch(void* const* d_in, const int* in_sizes, int n_in,
                              void* d_out, int out_size, void* d_ws, size_t ws_size,
                              hipStream_t stream) {
    const float* x    = (const float*)d_in[0];
    const int*   eidx = (const int*)d_in[1];
    const int*   batch= (const int*)d_in[2];
    const float* W0 = (const float*)d_in[3];  const float* b0 = (const float*)d_in[4];
    const float* W1 = (const float*)d_in[5];  const float* b1 = (const float*)d_in[6];
    const float* W2 = (const float*)d_in[7];  const float* b2 = (const float*)d_in[8];
    const float* Wc1= (const float*)d_in[9];  const float* bc1= (const float*)d_in[10];
    const float* Wc2= (const float*)d_in[11]; const float* bc2= (const float*)d_in[12];
    float* out = (float*)d_out;

    const int N   = in_sizes[2];       // 50000
    const int E   = in_sizes[1] / 2;   // 500000
    const int DIN = in_sizes[0] / N;   // 128
    const int DH  = in_sizes[4];       // 256
    const int* src = eidx;
    const int* dst = eidx + E;

    char* p = (char*)d_ws;
    auto alloc = [&](size_t bytes) {
        char* r = p;
        p += (bytes + 255) & ~(size_t)255;
        return (void*)r;
    };
    __half* hbuf = (__half*)alloc((size_t)N * DH * 2);   // gemm out (fp16), agg gather in
    __half* ha   = (__half*)alloc((size_t)N * DH * 2);   // agg out / gemm A in (fp16)
    __half* xh   = (__half*)alloc((size_t)N * DIN * 2);  // x in fp16
    __half* w0hi = (__half*)alloc((size_t)DH * DIN * 2);
    __half* w0lo = (__half*)alloc((size_t)DH * DIN * 2);
    __half* w1hi = (__half*)alloc((size_t)DH * DH * 2);
    __half* w1lo = (__half*)alloc((size_t)DH * DH * 2);
    __half* w2hi = (__half*)alloc((size_t)DH * DH * 2);
    __half* w2lo = (__half*)alloc((size_t)DH * DH * 2);
    int*   deg   = (int*)alloc((size_t)N * 4);
    float* gsum  = (float*)alloc(64 * (size_t)DH * 4);   // adjacent to deg: one memset covers both
    float* dinv  = (float*)alloc((size_t)N * 4);
    int*   part  = (int*)alloc((size_t)N * 4);
    int*   bsum  = (int*)alloc(256 * 4);
    int*   rowptr= (int*)alloc((size_t)(N + 1) * 4);
    int*   cursor= (int*)alloc((size_t)N * 4);
    int*   col   = (int*)alloc((size_t)E * 4);
    float* nrm   = (float*)alloc((size_t)E * 4);

    hipMemsetAsync(deg, 0, (size_t)((char*)gsum - (char*)deg) + 64 * (size_t)DH * 4, stream);

    const int nb = (N + 255) / 256;
    const int wtot = DIN * DH + 2 * DH * DH;
    const int wb = (wtot + 255) / 256;
    const int degB = (E + 255) / 256;
    const int nx = N * DIN;
    const int xb = (nx + 1023) / 1024;

    k_degx  <<<degB + xb, 256, 0, stream>>>(dst, E, deg, degB, x, xh, nx);
    k_scan1w<<<nb + wb, 256, 0, stream>>>(deg, N, nb, part, bsum, dinv,
                                          W0, w0hi, w0lo, W1, w1hi, w1lo, W2, w2hi, w2lo, DIN, DH);
    k_scan3 <<<nb, 256, 0, stream>>>(part, bsum, nb, N, E, rowptr, cursor);
    k_fill  <<<(E + 255) / 256, 256, 0, stream>>>(src, dst, E, dinv, cursor, col, nrm);

    dim3 gemmGrid(DH / 128, (N + 127) / 128);

    // layer 0: agg(x fp16) -> fp16 A -> gemm(relu(.W0+b0)) -> fp16 H
    k_agg128<<<(N + 7) / 8, 256, 0, stream>>>(xh, rowptr, col, nrm, dinv, ha, N);
    k_gemm_mfma<<<gemmGrid, 256, 0, stream>>>(ha, w0hi, w0lo, b0, hbuf, N, DIN);
    // layer 1
    k_agg256<<<(N + 3) / 4, 256, 0, stream>>>(hbuf, rowptr, col, nrm, dinv, ha, N);
    k_gemm_mfma<<<gemmGrid, 256, 0, stream>>>(ha, w1hi, w1lo, b1, hbuf, N, DH);
    // layer 2 (fused pooling epilogue)
    k_agg256<<<(N + 3) / 4, 256, 0, stream>>>(hbuf, rowptr, col, nrm, dinv, ha, N);
    k_gemm_pool<<<gemmGrid, 256, 0, stream>>>(ha, w2hi, w2lo, b2, batch, gsum, N, DH);

    k_poolcls<<<64, 256, 0, stream>>>(gsum, batch, N, Wc1, bc1, Wc2, bc2, out);
}

// Round 15
// 367.031 us; speedup vs baseline: 1.0860x; 1.0069x over previous
//
#include <hip/hip_runtime.h>
#include <hip/hip_fp16.h>

typedef _Float16 f16x8 __attribute__((ext_vector_type(8)));  // 8 fp16 = 4 VGPRs (MFMA A/B)
typedef float fx4 __attribute__((ext_vector_type(4)));       // MFMA acc

#define AS_G(p) ((const __attribute__((address_space(1))) void*)(p))
#define AS_L(p) ((__attribute__((address_space(3))) void*)(p))

struct __align__(8) half4 { __half2 lo, hi; };
struct __align__(8) edge_t { int u; float w; };   // paired edge record: one 8B store/load

// fp16 two-term split for weights: hi = fp16(w), lo = fp16(w - hi)  (combined ~2^-23 rel)
__device__ inline void split2h(float a, __half& hi, __half& lo) {
    hi = __float2half(a);
    lo = __float2half(a - __half2float(hi));
}

// ===================== graph preprocessing =====================

// fused dispatch: blocks [0,degB) histogram degrees (4 edges/thread); blocks [degB,..) x -> fp16.
__global__ void k_degx(const int* __restrict__ dst, int E, int* __restrict__ deg, int degB,
                       const float* __restrict__ x, __half* __restrict__ xh, int nx) {
    if (blockIdx.x < (unsigned)degB) {
        int i = (blockIdx.x * 256 + threadIdx.x) * 4;
        if (i + 4 <= E) {
            int4 d4 = *(const int4*)&dst[i];
            atomicAdd(&deg[d4.x], 1);
            atomicAdd(&deg[d4.y], 1);
            atomicAdd(&deg[d4.z], 1);
            atomicAdd(&deg[d4.w], 1);
        } else {
            for (int j = i; j < E; ++j) atomicAdd(&deg[dst[j]], 1);
        }
    } else {
        int i = (blockIdx.x - degB) * 1024 + threadIdx.x * 4;
        if (i < nx) {
            float4 v = *(const float4*)&x[i];
            __half2 h0(__float2half(v.x), __float2half(v.y));
            __half2 h1(__float2half(v.z), __float2half(v.w));
            *(__half2*)&xh[i] = h0;
            *(__half2*)&xh[i + 2] = h1;
        }
    }
}

// fused dispatch: blocks [0,nb) deg-scan + dinv; blocks [nb,..) split/transpose weights to fp16 hi/lo.
__global__ void k_scan1w(const int* __restrict__ deg, int N, int nb,
                         int* __restrict__ part, int* __restrict__ bsum, float* __restrict__ dinv,
                         const float* __restrict__ W0, __half* __restrict__ h0, __half* __restrict__ l0,
                         const float* __restrict__ W1, __half* __restrict__ h1, __half* __restrict__ l1,
                         const float* __restrict__ W2, __half* __restrict__ h2, __half* __restrict__ l2,
                         int DIN, int DH) {
    __shared__ int s[256];
    if (blockIdx.x < (unsigned)nb) {
        int i = blockIdx.x * 256 + threadIdx.x;
        int v = (i < N) ? deg[i] : 0;
        if (i < N) dinv[i] = 1.0f / sqrtf((float)(v + 1));  // +1 self-loop
        s[threadIdx.x] = v;
        __syncthreads();
        for (int off = 1; off < 256; off <<= 1) {
            int t = (threadIdx.x >= off) ? s[threadIdx.x - off] : 0;
            __syncthreads();
            s[threadIdx.x] += t;
            __syncthreads();
        }
        if (i < N) part[i] = s[threadIdx.x] - v;
        if (threadIdx.x == 255) bsum[blockIdx.x] = s[255];
    } else {
        int i = (blockIdx.x - nb) * 256 + threadIdx.x;
        const int n0 = DIN * DH, n1 = DH * DH;
        const float* W; __half *hT, *lT; int K, li;
        if (i < n0) { W = W0; hT = h0; lT = l0; K = DIN; li = i; }
        else if (i < n0 + n1) { W = W1; hT = h1; lT = l1; K = DH; li = i - n0; }
        else if (i < n0 + 2 * n1) { W = W2; hT = h2; lT = l2; K = DH; li = i - n0 - n1; }
        else return;
        int k = li / DH, n = li - k * DH;
        __half h, l;
        split2h(W[li], h, l);
        hT[(size_t)n * K + k] = h;
        lT[(size_t)n * K + k] = l;
    }
}

// rowptr build; each block reduces the raw per-block sums itself (nb <= 256).
__global__ void k_scan3(const int* __restrict__ part, const int* __restrict__ bsum, int nb,
                        int N, int E, int* __restrict__ rowptr, int* __restrict__ cursor) {
    __shared__ int s[256];
    const int t = threadIdx.x;
    s[t] = (t < nb && t < (int)blockIdx.x) ? bsum[t] : 0;
    __syncthreads();
    for (int off = 128; off > 0; off >>= 1) {
        if (t < off) s[t] += s[t + off];
        __syncthreads();
    }
    const int base = s[0];
    int i = blockIdx.x * 256 + t;
    if (i < N) {
        int v = part[i] + base;
        rowptr[i] = v;
        cursor[i] = v;
    }
    if (i == 0) rowptr[N] = E;
}

__global__ void k_fill(const int* __restrict__ src, const int* __restrict__ dst, int E,
                       const float* __restrict__ dinv, int* __restrict__ cursor,
                       edge_t* __restrict__ edg) {
    int e = blockIdx.x * blockDim.x + threadIdx.x;
    if (e < E) {
        int s = src[e], d = dst[e];
        int p = atomicAdd(&cursor[d], 1);
        edge_t ed;
        ed.u = s;
        ed.w = dinv[s] * dinv[d];
        edg[p] = ed;   // one 8B scattered store (was two 4B stores to two arrays)
    }
}

// ===================== fp16 MFMA GEMM (A single fp16, W fp16 hi+lo), bias/ReLU, fp16 out ===
// C = A*Whi + A*Wlo. Single-buffered (dbuf was neutral, r13). LDS 24KB.

__device__ __forceinline__ void gemm_core(
    const __half* __restrict__ Aop, const __half* __restrict__ BhiT, const __half* __restrict__ BloT,
    __half* smem, int Nrows, int K, int row0, int col0,
    int wid, int lane, int wrow, int wcol, int quad, int l16, fx4 (&acc)[4][4]) {
    const __half* gp[6];
    int ldsoff[6];
#pragma unroll
    for (int j = 0; j < 6; ++j) {
        int L = wid * 6 + j;
        int arr = L >> 3, slot = L & 7;
        int r = 16 * slot + (lane >> 2);
        int s = lane & 3;
        int q = (s - (r >> 1)) & 3;              // XOR swizzle folded into global addr
        const __half* garr = (arr == 0) ? Aop : (arr == 1) ? BhiT : BloT;
        int grow = (arr == 0) ? min(row0 + r, Nrows - 1) : (col0 + r);
        gp[j] = garr + (size_t)grow * K + q * 8;
        ldsoff[j] = arr * 8192 + slot * 1024;
    }

    const __half* sA   = smem;
    const __half* sBhi = smem + 128 * 32;
    const __half* sBlo = smem + 2 * 128 * 32;

    int aidx[4], bidx[4];
#pragma unroll
    for (int t = 0; t < 4; ++t) {
        int ra = wrow * 64 + t * 16 + l16;
        aidx[t] = ra * 32 + ((quad + (ra >> 1)) & 3) * 8;
        int rb = wcol * 64 + t * 16 + l16;
        bidx[t] = rb * 32 + ((quad + (rb >> 1)) & 3) * 8;
    }

    for (int k0 = 0; k0 < K; k0 += 32) {
#pragma unroll
        for (int j = 0; j < 6; ++j)
            __builtin_amdgcn_global_load_lds(AS_G(gp[j] + k0), AS_L((char*)smem + ldsoff[j]), 16, 0, 0);
        __syncthreads();

        f16x8 a[4];
#pragma unroll
        for (int mi = 0; mi < 4; ++mi) a[mi] = *(const f16x8*)&sA[aidx[mi]];
#pragma unroll
        for (int nj = 0; nj < 4; ++nj) {
            f16x8 bh = *(const f16x8*)&sBhi[bidx[nj]];
            f16x8 bl = *(const f16x8*)&sBlo[bidx[nj]];
#pragma unroll
            for (int mi = 0; mi < 4; ++mi) {
                acc[mi][nj] = __builtin_amdgcn_mfma_f32_16x16x32_f16(a[mi], bh, acc[mi][nj], 0, 0, 0);
                acc[mi][nj] = __builtin_amdgcn_mfma_f32_16x16x32_f16(a[mi], bl, acc[mi][nj], 0, 0, 0);
            }
        }
        __syncthreads();
    }
}

__global__ __launch_bounds__(256) void k_gemm_mfma(
    const __half* __restrict__ Aop, const __half* __restrict__ BhiT, const __half* __restrict__ BloT,
    const float* __restrict__ bias, __half* __restrict__ C, int Nrows, int K) {
    __shared__ __align__(16) __half smem[3 * 128 * 32];
    const int tid = threadIdx.x;
    const int wid = tid >> 6, lane = tid & 63;
    const int row0 = blockIdx.y * 128, col0 = blockIdx.x * 128;
    const int wrow = wid & 1, wcol = wid >> 1;
    const int quad = lane >> 4, l16 = lane & 15;

    fx4 acc[4][4] = {};
    gemm_core(Aop, BhiT, BloT, smem, Nrows, K, row0, col0, wid, lane, wrow, wcol, quad, l16, acc);

    // C/D layout: col = lane&15, row = quad*4 + reg  [m89-verified, dtype-independent]
#pragma unroll
    for (int mi = 0; mi < 4; ++mi) {
        const int rbase = row0 + wrow * 64 + mi * 16 + quad * 4;
#pragma unroll
        for (int nj = 0; nj < 4; ++nj) {
            const int c = col0 + wcol * 64 + nj * 16 + l16;
            const float bc = bias[c];
#pragma unroll
            for (int reg = 0; reg < 4; ++reg) {
                int r = rbase + reg;
                if (r < Nrows) C[(size_t)r * 256 + c] = __float2half(fmaxf(acc[mi][nj][reg] + bc, 0.f));
            }
        }
    }
}

// Layer-2 variant: relu(acc+bias) pooled per-graph into gsum[64][256]
__global__ __launch_bounds__(256) void k_gemm_pool(
    const __half* __restrict__ Aop, const __half* __restrict__ BhiT, const __half* __restrict__ BloT,
    const float* __restrict__ bias, const int* __restrict__ batch,
    float* __restrict__ gsum, int Nrows, int K) {
    __shared__ __align__(16) __half smem[3 * 128 * 32];
    const int tid = threadIdx.x;
    const int wid = tid >> 6, lane = tid & 63;
    const int row0 = blockIdx.y * 128, col0 = blockIdx.x * 128;
    const int wrow = wid & 1, wcol = wid >> 1;
    const int quad = lane >> 4, l16 = lane & 15;

    fx4 acc[4][4] = {};
    gemm_core(Aop, BhiT, BloT, smem, Nrows, K, row0, col0, wid, lane, wrow, wcol, quad, l16, acc);

    int bg[4][4];
#pragma unroll
    for (int mi = 0; mi < 4; ++mi)
#pragma unroll
        for (int reg = 0; reg < 4; ++reg) {
            int r = row0 + wrow * 64 + mi * 16 + quad * 4 + reg;
            bg[mi][reg] = (r < Nrows) ? batch[r] : -1;
        }
    const int gfirst = batch[row0 < Nrows ? row0 : (Nrows - 1)];
    const int glast  = batch[min(row0 + 127, Nrows - 1)];

#pragma unroll
    for (int nj = 0; nj < 4; ++nj) {
        const int c = col0 + wcol * 64 + nj * 16 + l16;
        const float bc = bias[c];
        for (int g = gfirst; g <= glast; ++g) {
            float s = 0.f;
#pragma unroll
            for (int mi = 0; mi < 4; ++mi)
#pragma unroll
                for (int reg = 0; reg < 4; ++reg)
                    if (bg[mi][reg] == g) s += fmaxf(acc[mi][nj][reg] + bc, 0.f);
            s += __shfl_xor(s, 16);
            s += __shfl_xor(s, 32);
            if (quad == 0) atomicAdd(&gsum[g * 256 + c], s);
        }
    }
}

// ===================== aggregation (fp16 gather, fp32 accumulate, fp16 out) =============
// WAVE-PER-NODE (proven best); edge stream is now one 8B record per edge.

__global__ __launch_bounds__(256) void k_agg256(const __half* __restrict__ H, const int* __restrict__ rowptr,
                                                const edge_t* __restrict__ edg,
                                                const float* __restrict__ dinv,
                                                __half* __restrict__ outA, int N) {
    const int wave = threadIdx.x >> 6, lane = threadIdx.x & 63;
    const int v = blockIdx.x * 4 + wave;
    if (v >= N) return;

    const float di = dinv[v];
    const float selfn = di * di;
    half4 hv = ((const half4*)&H[(size_t)v * 256])[lane];
    float2 s0 = __half22float2(hv.lo), s1 = __half22float2(hv.hi);
    float ax = selfn * s0.x, ay = selfn * s0.y, az = selfn * s1.x, aw = selfn * s1.y;

    int e = rowptr[v];
    const int end = rowptr[v + 1];
    for (; e + 8 <= end; e += 8) {
        edge_t ed[8]; half4 g[8];
#pragma unroll
        for (int j = 0; j < 8; ++j) ed[j] = edg[e + j];
#pragma unroll
        for (int j = 0; j < 8; ++j) g[j] = ((const half4*)&H[(size_t)ed[j].u * 256])[lane];
#pragma unroll
        for (int j = 0; j < 8; ++j) {
            float2 f0 = __half22float2(g[j].lo), f1 = __half22float2(g[j].hi);
            ax += ed[j].w * f0.x; ay += ed[j].w * f0.y; az += ed[j].w * f1.x; aw += ed[j].w * f1.y;
        }
    }
    for (; e < end; ++e) {
        edge_t ed = edg[e];
        half4 g = ((const half4*)&H[(size_t)ed.u * 256])[lane];
        float2 f0 = __half22float2(g.lo), f1 = __half22float2(g.hi);
        ax += ed.w * f0.x; ay += ed.w * f0.y; az += ed.w * f1.x; aw += ed.w * f1.y;
    }

    half4 o;
    o.lo = __floats2half2_rn(ax, ay);
    o.hi = __floats2half2_rn(az, aw);
    ((half4*)outA)[(size_t)v * 64 + lane] = o;
}

__global__ __launch_bounds__(256) void k_agg128(const __half* __restrict__ X, const int* __restrict__ rowptr,
                                                const edge_t* __restrict__ edg,
                                                const float* __restrict__ dinv,
                                                __half* __restrict__ outA, int N) {
    const int half = threadIdx.x >> 5, sub = threadIdx.x & 31;
    const int v = blockIdx.x * 8 + half;
    if (v >= N) return;

    const float di = dinv[v];
    const float selfn = di * di;
    half4 hv = ((const half4*)&X[(size_t)v * 128])[sub];
    float2 s0 = __half22float2(hv.lo), s1 = __half22float2(hv.hi);
    float ax = selfn * s0.x, ay = selfn * s0.y, az = selfn * s1.x, aw = selfn * s1.y;

    int e = rowptr[v];
    const int end = rowptr[v + 1];
    for (; e + 4 <= end; e += 4) {
        edge_t ed[4]; half4 g[4];
#pragma unroll
        for (int j = 0; j < 4; ++j) ed[j] = edg[e + j];
#pragma unroll
        for (int j = 0; j < 4; ++j) g[j] = ((const half4*)&X[(size_t)ed[j].u * 128])[sub];
#pragma unroll
        for (int j = 0; j < 4; ++j) {
            float2 f0 = __half22float2(g[j].lo), f1 = __half22float2(g[j].hi);
            ax += ed[j].w * f0.x; ay += ed[j].w * f0.y; az += ed[j].w * f1.x; aw += ed[j].w * f1.y;
        }
    }
    for (; e < end; ++e) {
        edge_t ed = edg[e];
        half4 g = ((const half4*)&X[(size_t)ed.u * 128])[sub];
        float2 f0 = __half22float2(g.lo), f1 = __half22float2(g.hi);
        ax += ed.w * f0.x; ay += ed.w * f0.y; az += ed.w * f1.x; aw += ed.w * f1.y;
    }

    half4 o;
    o.lo = __floats2half2_rn(ax, ay);
    o.hi = __floats2half2_rn(az, aw);
    ((half4*)outA)[(size_t)v * 32 + sub] = o;
}

// ===================== fused mean-pool finalize + classifier head =====================

__global__ __launch_bounds__(256) void k_poolcls(const float* __restrict__ gsum, const int* __restrict__ batch,
                                                 int N,
                                                 const float* __restrict__ Wc1, const float* __restrict__ bc1,
                                                 const float* __restrict__ Wc2, const float* __restrict__ bc2,
                                                 float* __restrict__ out) {
    __shared__ float sg[256], sh[256];
    __shared__ int bounds[2];
    const int b = blockIdx.x, t = threadIdx.x;
    if (t < 2) {
        int target = b + t;
        int lo = 0, hi = N;
        while (lo < hi) {
            int mid = (lo + hi) >> 1;
            if (batch[mid] < target) lo = mid + 1; else hi = mid;
        }
        bounds[t] = lo;
    }
    __syncthreads();
    const float c = (float)(bounds[1] - bounds[0]);
    sg[t] = gsum[b * 256 + t] / fmaxf(c, 1.0f);
    __syncthreads();
    float acc = bc1[t];
    for (int k = 0; k < 256; ++k) acc += sg[k] * Wc1[k * 256 + t];
    sh[t] = fmaxf(acc, 0.f);
    __syncthreads();
    if (t < 5) {
        float o = bc2[t];
        for (int k = 0; k < 256; ++k) o += sh[k] * Wc2[k * 5 + t];
        out[b * 5 + t] = o;
    }
}

// ===================== launch =====================

extern "C" void kernel_launch(void* const* d_in, const int* in_sizes, int n_in,
                              void* d_out, int out_size, void* d_ws, size_t ws_size,
                              hipStream_t stream) {
    const float* x    = (const float*)d_in[0];
    const int*   eidx = (const int*)d_in[1];
    const int*   batch= (const int*)d_in[2];
    const float* W0 = (const float*)d_in[3];  const float* b0 = (const float*)d_in[4];
    const float* W1 = (const float*)d_in[5];  const float* b1 = (const float*)d_in[6];
    const float* W2 = (const float*)d_in[7];  const float* b2 = (const float*)d_in[8];
    const float* Wc1= (const float*)d_in[9];  const float* bc1= (const float*)d_in[10];
    const float* Wc2= (const float*)d_in[11]; const float* bc2= (const float*)d_in[12];
    float* out = (float*)d_out;

    const int N   = in_sizes[2];       // 50000
    const int E   = in_sizes[1] / 2;   // 500000
    const int DIN = in_sizes[0] / N;   // 128
    const int DH  = in_sizes[4];       // 256
    const int* src = eidx;
    const int* dst = eidx + E;

    char* p = (char*)d_ws;
    auto alloc = [&](size_t bytes) {
        char* r = p;
        p += (bytes + 255) & ~(size_t)255;
        return (void*)r;
    };
    __half* hbuf = (__half*)alloc((size_t)N * DH * 2);   // gemm out (fp16), agg gather in
    __half* ha   = (__half*)alloc((size_t)N * DH * 2);   // agg out / gemm A in (fp16)
    __half* xh   = (__half*)alloc((size_t)N * DIN * 2);  // x in fp16
    __half* w0hi = (__half*)alloc((size_t)DH * DIN * 2);
    __half* w0lo = (__half*)alloc((size_t)DH * DIN * 2);
    __half* w1hi = (__half*)alloc((size_t)DH * DH * 2);
    __half* w1lo = (__half*)alloc((size_t)DH * DH * 2);
    __half* w2hi = (__half*)alloc((size_t)DH * DH * 2);
    __half* w2lo = (__half*)alloc((size_t)DH * DH * 2);
    int*   deg   = (int*)alloc((size_t)N * 4);
    float* gsum  = (float*)alloc(64 * (size_t)DH * 4);   // adjacent to deg: one memset covers both
    float* dinv  = (float*)alloc((size_t)N * 4);
    int*   part  = (int*)alloc((size_t)N * 4);
    int*   bsum  = (int*)alloc(256 * 4);
    int*   rowptr= (int*)alloc((size_t)(N + 1) * 4);
    int*   cursor= (int*)alloc((size_t)N * 4);
    edge_t* edg  = (edge_t*)alloc((size_t)E * 8);

    hipMemsetAsync(deg, 0, (size_t)((char*)gsum - (char*)deg) + 64 * (size_t)DH * 4, stream);

    const int nb = (N + 255) / 256;
    const int wtot = DIN * DH + 2 * DH * DH;
    const int wb = (wtot + 255) / 256;
    const int degB = (E + 1023) / 1024;
    const int nx = N * DIN;
    const int xb = (nx + 1023) / 1024;

    k_degx  <<<degB + xb, 256, 0, stream>>>(dst, E, deg, degB, x, xh, nx);
    k_scan1w<<<nb + wb, 256, 0, stream>>>(deg, N, nb, part, bsum, dinv,
                                          W0, w0hi, w0lo, W1, w1hi, w1lo, W2, w2hi, w2lo, DIN, DH);
    k_scan3 <<<nb, 256, 0, stream>>>(part, bsum, nb, N, E, rowptr, cursor);
    k_fill  <<<(E + 255) / 256, 256, 0, stream>>>(src, dst, E, dinv, cursor, edg);

    dim3 gemmGrid(DH / 128, (N + 127) / 128);

    // layer 0: agg(x fp16) -> fp16 A -> gemm(relu(.W0+b0)) -> fp16 H
    k_agg128<<<(N + 7) / 8, 256, 0, stream>>>(xh, rowptr, edg, dinv, ha, N);
    k_gemm_mfma<<<gemmGrid, 256, 0, stream>>>(ha, w0hi, w0lo, b0, hbuf, N, DIN);
    // layer 1
    k_agg256<<<(N + 3) / 4, 256, 0, stream>>>(hbuf, rowptr, edg, dinv, ha, N);
    k_gemm_mfma<<<gemmGrid, 256, 0, stream>>>(ha, w1hi, w1lo, b1, hbuf, N, DH);
    // layer 2 (fused pooling epilogue)
    k_agg256<<<(N + 3) / 4, 256, 0, stream>>>(hbuf, rowptr, edg, dinv, ha, N);
    k_gemm_pool<<<gemmGrid, 256, 0, stream>>>(ha, w2hi, w2lo, b2, batch, gsum, N, DH);

    k_poolcls<<<64, 256, 0, stream>>>(gsum, batch, N, Wc1, bc1, Wc2, bc2, out);
}

// Round 16
// 339.695 us; speedup vs baseline: 1.1734x; 1.0805x over previous
//
#include <hip/hip_runtime.h>
#include <hip/hip_fp16.h>

typedef _Float16 f16x8 __attribute__((ext_vector_type(8)));  // 8 fp16 = 4 VGPRs (MFMA A/B)
typedef float fx4 __attribute__((ext_vector_type(4)));       // MFMA acc

#define AS_G(p) ((const __attribute__((address_space(1))) void*)(p))
#define AS_L(p) ((__attribute__((address_space(3))) void*)(p))

struct __align__(8) half4 { __half2 lo, hi; };
struct __align__(8) edge_t { int u; float w; };   // paired edge record: one 8B store/load

// fp16 two-term split for weights: hi = fp16(w), lo = fp16(w - hi)  (combined ~2^-23 rel)
__device__ inline void split2h(float a, __half& hi, __half& lo) {
    hi = __float2half(a);
    lo = __float2half(a - __half2float(hi));
}

// ===================== graph preprocessing =====================

// fused dispatch: blocks [0,degB) histogram degrees (4 edges/thread); blocks [degB,..) x -> fp16.
__global__ void k_degx(const int* __restrict__ dst, int E, int* __restrict__ deg, int degB,
                       const float* __restrict__ x, __half* __restrict__ xh, int nx) {
    if (blockIdx.x < (unsigned)degB) {
        int i = (blockIdx.x * 256 + threadIdx.x) * 4;
        if (i + 4 <= E) {
            int4 d4 = *(const int4*)&dst[i];
            atomicAdd(&deg[d4.x], 1);
            atomicAdd(&deg[d4.y], 1);
            atomicAdd(&deg[d4.z], 1);
            atomicAdd(&deg[d4.w], 1);
        } else {
            for (int j = i; j < E; ++j) atomicAdd(&deg[dst[j]], 1);
        }
    } else {
        int i = (blockIdx.x - degB) * 1024 + threadIdx.x * 4;
        if (i < nx) {
            float4 v = *(const float4*)&x[i];
            __half2 h0(__float2half(v.x), __float2half(v.y));
            __half2 h1(__float2half(v.z), __float2half(v.w));
            *(__half2*)&xh[i] = h0;
            *(__half2*)&xh[i + 2] = h1;
        }
    }
}

// fused dispatch: blocks [0,nb) deg-scan + dinv; blocks [nb,..) split/transpose weights to fp16 hi/lo.
__global__ void k_scan1w(const int* __restrict__ deg, int N, int nb,
                         int* __restrict__ part, int* __restrict__ bsum, float* __restrict__ dinv,
                         const float* __restrict__ W0, __half* __restrict__ h0, __half* __restrict__ l0,
                         const float* __restrict__ W1, __half* __restrict__ h1, __half* __restrict__ l1,
                         const float* __restrict__ W2, __half* __restrict__ h2, __half* __restrict__ l2,
                         int DIN, int DH) {
    __shared__ int s[256];
    if (blockIdx.x < (unsigned)nb) {
        int i = blockIdx.x * 256 + threadIdx.x;
        int v = (i < N) ? deg[i] : 0;
        if (i < N) dinv[i] = 1.0f / sqrtf((float)(v + 1));  // +1 self-loop
        s[threadIdx.x] = v;
        __syncthreads();
        for (int off = 1; off < 256; off <<= 1) {
            int t = (threadIdx.x >= off) ? s[threadIdx.x - off] : 0;
            __syncthreads();
            s[threadIdx.x] += t;
            __syncthreads();
        }
        if (i < N) part[i] = s[threadIdx.x] - v;
        if (threadIdx.x == 255) bsum[blockIdx.x] = s[255];
    } else {
        int i = (blockIdx.x - nb) * 256 + threadIdx.x;
        const int n0 = DIN * DH, n1 = DH * DH;
        const float* W; __half *hT, *lT; int K, li;
        if (i < n0) { W = W0; hT = h0; lT = l0; K = DIN; li = i; }
        else if (i < n0 + n1) { W = W1; hT = h1; lT = l1; K = DH; li = i - n0; }
        else if (i < n0 + 2 * n1) { W = W2; hT = h2; lT = l2; K = DH; li = i - n0 - n1; }
        else return;
        int k = li / DH, n = li - k * DH;
        __half h, l;
        split2h(W[li], h, l);
        hT[(size_t)n * K + k] = h;
        lT[(size_t)n * K + k] = l;
    }
}

// rowptr build; each block reduces the raw per-block sums itself (nb <= 256).
__global__ void k_scan3(const int* __restrict__ part, const int* __restrict__ bsum, int nb,
                        int N, int E, int* __restrict__ rowptr, int* __restrict__ cursor) {
    __shared__ int s[256];
    const int t = threadIdx.x;
    s[t] = (t < nb && t < (int)blockIdx.x) ? bsum[t] : 0;
    __syncthreads();
    for (int off = 128; off > 0; off >>= 1) {
        if (t < off) s[t] += s[t + off];
        __syncthreads();
    }
    const int base = s[0];
    int i = blockIdx.x * 256 + t;
    if (i < N) {
        int v = part[i] + base;
        rowptr[i] = v;
        cursor[i] = v;
    }
    if (i == 0) rowptr[N] = E;
}

__global__ void k_fill(const int* __restrict__ src, const int* __restrict__ dst, int E,
                       const float* __restrict__ dinv, int* __restrict__ cursor,
                       edge_t* __restrict__ edg) {
    int e = blockIdx.x * blockDim.x + threadIdx.x;
    if (e < E) {
        int s = src[e], d = dst[e];
        int p = atomicAdd(&cursor[d], 1);
        edge_t ed;
        ed.u = s;
        ed.w = dinv[s] * dinv[d];
        edg[p] = ed;
    }
}

// ===================== fp16 MFMA GEMM, BN=256 (full output width per block) =============
// Block = 128 rows x 256 cols, 512 threads (8 waves, 2 row-groups x 4 col-groups of
// 64x64 wave tiles). A-rows fetched ONCE per layer (was 2x with the (2,391) grid);
// half the blocks. Per-wave math identical to the proven r14 kernel => bit-identical.
// LDS: A 8KB + Bhi 16KB + Blo 16KB = 40KB -> 4 blocks/CU. Single-buffered (r13: dbuf neutral).

__device__ __forceinline__ void gemm_core(
    const __half* __restrict__ Aop, const __half* __restrict__ BhiT, const __half* __restrict__ BloT,
    __half* smem, int Nrows, int K, int row0,
    int wid, int lane, int wrow, int wcol, int quad, int l16, fx4 (&acc)[4][4]) {
    // 40 1KB stage-slots: A 0..7 (128 rows), Bhi 8..23 (256 rows), Blo 24..39.
    const __half* gp[5];
    int ldsoff[5];
#pragma unroll
    for (int j = 0; j < 5; ++j) {
        int L = wid * 5 + j;
        int arr, slot;
        if (L < 8) { arr = 0; slot = L; }
        else if (L < 24) { arr = 1; slot = L - 8; }
        else { arr = 2; slot = L - 24; }
        int r = 16 * slot + (lane >> 2);
        int s = lane & 3;
        int q = (s - (r >> 1)) & 3;              // XOR swizzle folded into global addr
        const __half* garr = (arr == 0) ? Aop : (arr == 1) ? BhiT : BloT;
        int grow = (arr == 0) ? min(row0 + r, Nrows - 1) : r;
        gp[j] = garr + (size_t)grow * K + q * 8;
        ldsoff[j] = ((arr == 0) ? 0 : (arr == 1) ? 8192 : 24576) + slot * 1024;
    }

    const __half* sA   = smem;                   // 128 x 32
    const __half* sBhi = smem + 4096;            // 256 x 32 (byte off 8192)
    const __half* sBlo = smem + 12288;           // 256 x 32 (byte off 24576)

    int aidx[4], bidx[4];
#pragma unroll
    for (int t = 0; t < 4; ++t) {
        int ra = wrow * 64 + t * 16 + l16;
        aidx[t] = ra * 32 + ((quad + (ra >> 1)) & 3) * 8;
        int rb = wcol * 64 + t * 16 + l16;       // wcol in [0,4): covers 256 B-rows
        bidx[t] = rb * 32 + ((quad + (rb >> 1)) & 3) * 8;
    }

    for (int k0 = 0; k0 < K; k0 += 32) {
#pragma unroll
        for (int j = 0; j < 5; ++j)
            __builtin_amdgcn_global_load_lds(AS_G(gp[j] + k0), AS_L((char*)smem + ldsoff[j]), 16, 0, 0);
        __syncthreads();

        f16x8 a[4];
#pragma unroll
        for (int mi = 0; mi < 4; ++mi) a[mi] = *(const f16x8*)&sA[aidx[mi]];
#pragma unroll
        for (int nj = 0; nj < 4; ++nj) {
            f16x8 bh = *(const f16x8*)&sBhi[bidx[nj]];
            f16x8 bl = *(const f16x8*)&sBlo[bidx[nj]];
#pragma unroll
            for (int mi = 0; mi < 4; ++mi) {
                acc[mi][nj] = __builtin_amdgcn_mfma_f32_16x16x32_f16(a[mi], bh, acc[mi][nj], 0, 0, 0);
                acc[mi][nj] = __builtin_amdgcn_mfma_f32_16x16x32_f16(a[mi], bl, acc[mi][nj], 0, 0, 0);
            }
        }
        __syncthreads();
    }
}

__global__ __launch_bounds__(512) void k_gemm_mfma(
    const __half* __restrict__ Aop, const __half* __restrict__ BhiT, const __half* __restrict__ BloT,
    const float* __restrict__ bias, __half* __restrict__ C, int Nrows, int K) {
    __shared__ __align__(16) __half smem[20480];   // 40 KB
    const int tid = threadIdx.x;
    const int wid = tid >> 6, lane = tid & 63;
    const int row0 = blockIdx.x * 128;
    const int wrow = wid & 1, wcol = wid >> 1;     // 2 x 4 wave grid
    const int quad = lane >> 4, l16 = lane & 15;

    fx4 acc[4][4] = {};
    gemm_core(Aop, BhiT, BloT, smem, Nrows, K, row0, wid, lane, wrow, wcol, quad, l16, acc);

    // C/D layout: col = lane&15, row = quad*4 + reg  [m89-verified, dtype-independent]
#pragma unroll
    for (int mi = 0; mi < 4; ++mi) {
        const int rbase = row0 + wrow * 64 + mi * 16 + quad * 4;
#pragma unroll
        for (int nj = 0; nj < 4; ++nj) {
            const int c = wcol * 64 + nj * 16 + l16;
            const float bc = bias[c];
#pragma unroll
            for (int reg = 0; reg < 4; ++reg) {
                int r = rbase + reg;
                if (r < Nrows) C[(size_t)r * 256 + c] = __float2half(fmaxf(acc[mi][nj][reg] + bc, 0.f));
            }
        }
    }
}

// Layer-2 variant: relu(acc+bias) pooled per-graph into gsum[64][256]
__global__ __launch_bounds__(512) void k_gemm_pool(
    const __half* __restrict__ Aop, const __half* __restrict__ BhiT, const __half* __restrict__ BloT,
    const float* __restrict__ bias, const int* __restrict__ batch,
    float* __restrict__ gsum, int Nrows, int K) {
    __shared__ __align__(16) __half smem[20480];
    const int tid = threadIdx.x;
    const int wid = tid >> 6, lane = tid & 63;
    const int row0 = blockIdx.x * 128;
    const int wrow = wid & 1, wcol = wid >> 1;
    const int quad = lane >> 4, l16 = lane & 15;

    fx4 acc[4][4] = {};
    gemm_core(Aop, BhiT, BloT, smem, Nrows, K, row0, wid, lane, wrow, wcol, quad, l16, acc);

    int bg[4][4];
#pragma unroll
    for (int mi = 0; mi < 4; ++mi)
#pragma unroll
        for (int reg = 0; reg < 4; ++reg) {
            int r = row0 + wrow * 64 + mi * 16 + quad * 4 + reg;
            bg[mi][reg] = (r < Nrows) ? batch[r] : -1;
        }
    const int gfirst = batch[row0 < Nrows ? row0 : (Nrows - 1)];
    const int glast  = batch[min(row0 + 127, Nrows - 1)];

#pragma unroll
    for (int nj = 0; nj < 4; ++nj) {
        const int c = wcol * 64 + nj * 16 + l16;
        const float bc = bias[c];
        for (int g = gfirst; g <= glast; ++g) {
            float s = 0.f;
#pragma unroll
            for (int mi = 0; mi < 4; ++mi)
#pragma unroll
                for (int reg = 0; reg < 4; ++reg)
                    if (bg[mi][reg] == g) s += fmaxf(acc[mi][nj][reg] + bc, 0.f);
            s += __shfl_xor(s, 16);
            s += __shfl_xor(s, 32);
            if (quad == 0) atomicAdd(&gsum[g * 256 + c], s);
        }
    }
}

// ===================== aggregation (fp16 gather, fp32 accumulate, fp16 out) =============
// WAVE-PER-NODE (proven best across r8/r11 variants); one 8B edge record per edge.

__global__ __launch_bounds__(256) void k_agg256(const __half* __restrict__ H, const int* __restrict__ rowptr,
                                                const edge_t* __restrict__ edg,
                                                const float* __restrict__ dinv,
                                                __half* __restrict__ outA, int N) {
    const int wave = threadIdx.x >> 6, lane = threadIdx.x & 63;
    const int v = blockIdx.x * 4 + wave;
    if (v >= N) return;

    const float di = dinv[v];
    const float selfn = di * di;
    half4 hv = ((const half4*)&H[(size_t)v * 256])[lane];
    float2 s0 = __half22float2(hv.lo), s1 = __half22float2(hv.hi);
    float ax = selfn * s0.x, ay = selfn * s0.y, az = selfn * s1.x, aw = selfn * s1.y;

    int e = rowptr[v];
    const int end = rowptr[v + 1];
    for (; e + 8 <= end; e += 8) {
        edge_t ed[8]; half4 g[8];
#pragma unroll
        for (int j = 0; j < 8; ++j) ed[j] = edg[e + j];
#pragma unroll
        for (int j = 0; j < 8; ++j) g[j] = ((const half4*)&H[(size_t)ed[j].u * 256])[lane];
#pragma unroll
        for (int j = 0; j < 8; ++j) {
            float2 f0 = __half22float2(g[j].lo), f1 = __half22float2(g[j].hi);
            ax += ed[j].w * f0.x; ay += ed[j].w * f0.y; az += ed[j].w * f1.x; aw += ed[j].w * f1.y;
        }
    }
    for (; e < end; ++e) {
        edge_t ed = edg[e];
        half4 g = ((const half4*)&H[(size_t)ed.u * 256])[lane];
        float2 f0 = __half22float2(g.lo), f1 = __half22float2(g.hi);
        ax += ed.w * f0.x; ay += ed.w * f0.y; az += ed.w * f1.x; aw += ed.w * f1.y;
    }

    half4 o;
    o.lo = __floats2half2_rn(ax, ay);
    o.hi = __floats2half2_rn(az, aw);
    ((half4*)outA)[(size_t)v * 64 + lane] = o;
}

__global__ __launch_bounds__(256) void k_agg128(const __half* __restrict__ X, const int* __restrict__ rowptr,
                                                const edge_t* __restrict__ edg,
                                                const float* __restrict__ dinv,
                                                __half* __restrict__ outA, int N) {
    const int half = threadIdx.x >> 5, sub = threadIdx.x & 31;
    const int v = blockIdx.x * 8 + half;
    if (v >= N) return;

    const float di = dinv[v];
    const float selfn = di * di;
    half4 hv = ((const half4*)&X[(size_t)v * 128])[sub];
    float2 s0 = __half22float2(hv.lo), s1 = __half22float2(hv.hi);
    float ax = selfn * s0.x, ay = selfn * s0.y, az = selfn * s1.x, aw = selfn * s1.y;

    int e = rowptr[v];
    const int end = rowptr[v + 1];
    for (; e + 4 <= end; e += 4) {
        edge_t ed[4]; half4 g[4];
#pragma unroll
        for (int j = 0; j < 4; ++j) ed[j] = edg[e + j];
#pragma unroll
        for (int j = 0; j < 4; ++j) g[j] = ((const half4*)&X[(size_t)ed[j].u * 128])[sub];
#pragma unroll
        for (int j = 0; j < 4; ++j) {
            float2 f0 = __half22float2(g[j].lo), f1 = __half22float2(g[j].hi);
            ax += ed[j].w * f0.x; ay += ed[j].w * f0.y; az += ed[j].w * f1.x; aw += ed[j].w * f1.y;
        }
    }
    for (; e < end; ++e) {
        edge_t ed = edg[e];
        half4 g = ((const half4*)&X[(size_t)ed.u * 128])[sub];
        float2 f0 = __half22float2(g.lo), f1 = __half22float2(g.hi);
        ax += ed.w * f0.x; ay += ed.w * f0.y; az += ed.w * f1.x; aw += ed.w * f1.y;
    }

    half4 o;
    o.lo = __floats2half2_rn(ax, ay);
    o.hi = __floats2half2_rn(az, aw);
    ((half4*)outA)[(size_t)v * 32 + sub] = o;
}

// ===================== fused mean-pool finalize + classifier head =====================

__global__ __launch_bounds__(256) void k_poolcls(const float* __restrict__ gsum, const int* __restrict__ batch,
                                                 int N,
                                                 const float* __restrict__ Wc1, const float* __restrict__ bc1,
                                                 const float* __restrict__ Wc2, const float* __restrict__ bc2,
                                                 float* __restrict__ out) {
    __shared__ float sg[256], sh[256];
    __shared__ int bounds[2];
    const int b = blockIdx.x, t = threadIdx.x;
    if (t < 2) {
        int target = b + t;
        int lo = 0, hi = N;
        while (lo < hi) {
            int mid = (lo + hi) >> 1;
            if (batch[mid] < target) lo = mid + 1; else hi = mid;
        }
        bounds[t] = lo;
    }
    __syncthreads();
    const float c = (float)(bounds[1] - bounds[0]);
    sg[t] = gsum[b * 256 + t] / fmaxf(c, 1.0f);
    __syncthreads();
    float acc = bc1[t];
    for (int k = 0; k < 256; ++k) acc += sg[k] * Wc1[k * 256 + t];
    sh[t] = fmaxf(acc, 0.f);
    __syncthreads();
    if (t < 5) {
        float o = bc2[t];
        for (int k = 0; k < 256; ++k) o += sh[k] * Wc2[k * 5 + t];
        out[b * 5 + t] = o;
    }
}

// ===================== launch =====================

extern "C" void kernel_launch(void* const* d_in, const int* in_sizes, int n_in,
                              void* d_out, int out_size, void* d_ws, size_t ws_size,
                              hipStream_t stream) {
    const float* x    = (const float*)d_in[0];
    const int*   eidx = (const int*)d_in[1];
    const int*   batch= (const int*)d_in[2];
    const float* W0 = (const float*)d_in[3];  const float* b0 = (const float*)d_in[4];
    const float* W1 = (const float*)d_in[5];  const float* b1 = (const float*)d_in[6];
    const float* W2 = (const float*)d_in[7];  const float* b2 = (const float*)d_in[8];
    const float* Wc1= (const float*)d_in[9];  const float* bc1= (const float*)d_in[10];
    const float* Wc2= (const float*)d_in[11]; const float* bc2= (const float*)d_in[12];
    float* out = (float*)d_out;

    const int N   = in_sizes[2];       // 50000
    const int E   = in_sizes[1] / 2;   // 500000
    const int DIN = in_sizes[0] / N;   // 128
    const int DH  = in_sizes[4];       // 256
    const int* src = eidx;
    const int* dst = eidx + E;

    char* p = (char*)d_ws;
    auto alloc = [&](size_t bytes) {
        char* r = p;
        p += (bytes + 255) & ~(size_t)255;
        return (void*)r;
    };
    __half* hbuf = (__half*)alloc((size_t)N * DH * 2);   // gemm out (fp16), agg gather in
    __half* ha   = (__half*)alloc((size_t)N * DH * 2);   // agg out / gemm A in (fp16)
    __half* xh   = (__half*)alloc((size_t)N * DIN * 2);  // x in fp16
    __half* w0hi = (__half*)alloc((size_t)DH * DIN * 2);
    __half* w0lo = (__half*)alloc((size_t)DH * DIN * 2);
    __half* w1hi = (__half*)alloc((size_t)DH * DH * 2);
    __half* w1lo = (__half*)alloc((size_t)DH * DH * 2);
    __half* w2hi = (__half*)alloc((size_t)DH * DH * 2);
    __half* w2lo = (__half*)alloc((size_t)DH * DH * 2);
    int*   deg   = (int*)alloc((size_t)N * 4);
    float* gsum  = (float*)alloc(64 * (size_t)DH * 4);   // adjacent to deg: one memset covers both
    float* dinv  = (float*)alloc((size_t)N * 4);
    int*   part  = (int*)alloc((size_t)N * 4);
    int*   bsum  = (int*)alloc(256 * 4);
    int*   rowptr= (int*)alloc((size_t)(N + 1) * 4);
    int*   cursor= (int*)alloc((size_t)N * 4);
    edge_t* edg  = (edge_t*)alloc((size_t)E * 8);

    hipMemsetAsync(deg, 0, (size_t)((char*)gsum - (char*)deg) + 64 * (size_t)DH * 4, stream);

    const int nb = (N + 255) / 256;
    const int wtot = DIN * DH + 2 * DH * DH;
    const int wb = (wtot + 255) / 256;
    const int degB = (E + 1023) / 1024;
    const int nx = N * DIN;
    const int xb = (nx + 1023) / 1024;

    k_degx  <<<degB + xb, 256, 0, stream>>>(dst, E, deg, degB, x, xh, nx);
    k_scan1w<<<nb + wb, 256, 0, stream>>>(deg, N, nb, part, bsum, dinv,
                                          W0, w0hi, w0lo, W1, w1hi, w1lo, W2, w2hi, w2lo, DIN, DH);
    k_scan3 <<<nb, 256, 0, stream>>>(part, bsum, nb, N, E, rowptr, cursor);
    k_fill  <<<(E + 255) / 256, 256, 0, stream>>>(src, dst, E, dinv, cursor, edg);

    const int gemmBlocks = (N + 127) / 128;

    // layer 0: agg(x fp16) -> fp16 A -> gemm(relu(.W0+b0)) -> fp16 H
    k_agg128<<<(N + 7) / 8, 256, 0, stream>>>(xh, rowptr, edg, dinv, ha, N);
    k_gemm_mfma<<<gemmBlocks, 512, 0, stream>>>(ha, w0hi, w0lo, b0, hbuf, N, DIN);
    // layer 1
    k_agg256<<<(N + 3) / 4, 256, 0, stream>>>(hbuf, rowptr, edg, dinv, ha, N);
    k_gemm_mfma<<<gemmBlocks, 512, 0, stream>>>(ha, w1hi, w1lo, b1, hbuf, N, DH);
    // layer 2 (fused pooling epilogue)
    k_agg256<<<(N + 3) / 4, 256, 0, stream>>>(hbuf, rowptr, edg, dinv, ha, N);
    k_gemm_pool<<<gemmBlocks, 512, 0, stream>>>(ha, w2hi, w2lo, b2, batch, gsum, N, DH);

    k_poolcls<<<64, 256, 0, stream>>>(gsum, batch, N, Wc1, bc1, Wc2, bc2, out);
}